// Round 1
// baseline (3713.965 us; speedup 1.0000x reference)
//
#include <hip/hip_runtime.h>

#define NN 100000   // nodes
#define NE 800000   // edges
#define NG 256      // graphs
#define CH 96       // in/hidden channels
#define OC 16       // out channels

// ---------------- degree / dinv ----------------
__global__ __launch_bounds__(256) void k_deg_init(float* __restrict__ deg) {
    int i = blockIdx.x * 256 + threadIdx.x;
    if (i < NN) deg[i] = 1.0f;  // self-loop
}

__global__ __launch_bounds__(256) void k_deg_count(const int* __restrict__ dst,
                                                   float* __restrict__ deg) {
    int e = blockIdx.x * 256 + threadIdx.x;
    if (e < NE) atomicAdd(&deg[dst[e]], 1.0f);
}

__global__ __launch_bounds__(256) void k_deg_rsqrt(float* __restrict__ deg) {
    int i = blockIdx.x * 256 + threadIdx.x;
    if (i < NN) deg[i] = rsqrtf(deg[i]);  // deg -> dinv in place
}

// ---------------- GEMM: H = X @ W ; A = H*dinv^2 + b ----------------
// 32 nodes/block, 256 threads = 32 nodes x 8 col-groups of 12 cols.
// A may alias X: each block's X rows are staged to LDS before any write,
// and no other block touches those rows.
__global__ __launch_bounds__(256) void k_gemm96(const float* __restrict__ X,
                                                const float* __restrict__ W,
                                                const float* __restrict__ b,
                                                const float* __restrict__ dinv,
                                                float* __restrict__ H,
                                                float* __restrict__ A) {
    __shared__ __align__(16) float Ws[CH * CH];     // 36 KB
    __shared__ __align__(16) float Xs[32][CH + 1];  // padded: kills 8-way bank conflict

    const int tid = threadIdx.x;
    const int n0 = blockIdx.x * 32;

    // stage W (9216 floats) as float4
    const float4* W4 = reinterpret_cast<const float4*>(W);
    float4* Ws4 = reinterpret_cast<float4*>(Ws);
    for (int i = tid; i < CH * CH / 4; i += 256) Ws4[i] = W4[i];

    // stage X tile (32 x 96) as float4  (100000 % 32 == 0: no edge guard needed)
    for (int i = tid; i < 32 * CH / 4; i += 256) {
        int r = i / (CH / 4);
        int c = (i % (CH / 4)) * 4;
        float4 v = *reinterpret_cast<const float4*>(&X[(size_t)(n0 + r) * CH + c]);
        Xs[r][c] = v.x; Xs[r][c + 1] = v.y; Xs[r][c + 2] = v.z; Xs[r][c + 3] = v.w;
    }
    __syncthreads();

    const int nl = tid >> 3;        // node within tile
    const int c0 = (tid & 7) * 12;  // first col of this thread's 12

    float acc[12];
#pragma unroll
    for (int j = 0; j < 12; j++) acc[j] = 0.0f;

#pragma unroll 8
    for (int k = 0; k < CH; k++) {
        float xv = Xs[nl][k];
        const float* wr = &Ws[k * CH + c0];
        float4 w0 = *reinterpret_cast<const float4*>(wr);
        float4 w1 = *reinterpret_cast<const float4*>(wr + 4);
        float4 w2 = *reinterpret_cast<const float4*>(wr + 8);
        acc[0] += xv * w0.x;  acc[1] += xv * w0.y;  acc[2]  += xv * w0.z;  acc[3]  += xv * w0.w;
        acc[4] += xv * w1.x;  acc[5] += xv * w1.y;  acc[6]  += xv * w1.z;  acc[7]  += xv * w1.w;
        acc[8] += xv * w2.x;  acc[9] += xv * w2.y;  acc[10] += xv * w2.z;  acc[11] += xv * w2.w;
    }

    const int n = n0 + nl;
    const float di = dinv[n];
    const float d2 = di * di;
    float4 b0 = *reinterpret_cast<const float4*>(&b[c0]);
    float4 b1 = *reinterpret_cast<const float4*>(&b[c0 + 4]);
    float4 b2 = *reinterpret_cast<const float4*>(&b[c0 + 8]);

    float* hp = &H[(size_t)n * CH + c0];
    float* ap = &A[(size_t)n * CH + c0];
    float4 h0 = make_float4(acc[0], acc[1], acc[2], acc[3]);
    float4 h1 = make_float4(acc[4], acc[5], acc[6], acc[7]);
    float4 h2 = make_float4(acc[8], acc[9], acc[10], acc[11]);
    *reinterpret_cast<float4*>(hp) = h0;
    *reinterpret_cast<float4*>(hp + 4) = h1;
    *reinterpret_cast<float4*>(hp + 8) = h2;
    *reinterpret_cast<float4*>(ap) =
        make_float4(h0.x * d2 + b0.x, h0.y * d2 + b0.y, h0.z * d2 + b0.z, h0.w * d2 + b0.w);
    *reinterpret_cast<float4*>(ap + 4) =
        make_float4(h1.x * d2 + b1.x, h1.y * d2 + b1.y, h1.z * d2 + b1.z, h1.w * d2 + b1.w);
    *reinterpret_cast<float4*>(ap + 8) =
        make_float4(h2.x * d2 + b2.x, h2.y * d2 + b2.y, h2.z * d2 + b2.z, h2.w * d2 + b2.w);
}

// ---------------- edge scatter: A[dst] += H[src] * dinv[src]*dinv[dst] ----------------
// 24 threads per edge, float4 per thread: one coalesced 384B row gather per edge.
__global__ __launch_bounds__(256) void k_scatter(const int* __restrict__ src,
                                                 const int* __restrict__ dst,
                                                 const float* __restrict__ dinv,
                                                 const float* __restrict__ H,
                                                 float* __restrict__ A) {
    int idx = blockIdx.x * 256 + threadIdx.x;  // NE*24 = 19.2M < 2^31
    int e = idx / 24;
    int c4 = idx - e * 24;
    int s = src[e];
    int d = dst[e];
    float coef = dinv[s] * dinv[d];
    float4 v = *reinterpret_cast<const float4*>(&H[(size_t)s * CH + c4 * 4]);
    float* o = &A[(size_t)d * CH + c4 * 4];
    atomicAdd(o + 0, v.x * coef);
    atomicAdd(o + 1, v.y * coef);
    atomicAdd(o + 2, v.z * coef);
    atomicAdd(o + 3, v.w * coef);
}

__global__ __launch_bounds__(256) void k_relu(float* __restrict__ A) {
    int i = blockIdx.x * 256 + threadIdx.x;  // NN*96 = 9.6M
    A[i] = fmaxf(A[i], 0.0f);
}

// ---------------- pooling ----------------
__global__ __launch_bounds__(256) void k_zero(float* __restrict__ p, int n) {
    int i = blockIdx.x * 256 + threadIdx.x;
    if (i < n) p[i] = 0.0f;
}

__global__ __launch_bounds__(256) void k_pool(const int* __restrict__ batch,
                                              const float* __restrict__ A,
                                              float* __restrict__ sums,
                                              float* __restrict__ cnts) {
    int idx = blockIdx.x * 256 + threadIdx.x;  // NN*24
    int n = idx / 24;
    int c4 = idx - n * 24;
    int g = batch[n];
    float4 v = *reinterpret_cast<const float4*>(&A[(size_t)n * CH + c4 * 4]);
    float* o = &sums[(size_t)g * CH + c4 * 4];
    atomicAdd(o + 0, v.x);
    atomicAdd(o + 1, v.y);
    atomicAdd(o + 2, v.z);
    atomicAdd(o + 3, v.w);
    if (c4 == 0) atomicAdd(&cnts[g], 1.0f);
}

// out[g,o] = (sum_k sums[g,k]*Wlin[k,o]) / max(cnt[g],1)
__global__ __launch_bounds__(256) void k_final(const float* __restrict__ sums,
                                               const float* __restrict__ cnts,
                                               const float* __restrict__ Wlin,
                                               float* __restrict__ out) {
    int idx = blockIdx.x * 256 + threadIdx.x;
    if (idx >= NG * OC) return;
    int g = idx / OC;
    int o = idx - g * OC;
    float acc = 0.0f;
#pragma unroll 8
    for (int k = 0; k < CH; k++) acc += sums[g * CH + k] * Wlin[k * OC + o];
    float cnt = fmaxf(cnts[g], 1.0f);
    out[idx] = acc / cnt;
}

// ---------------- launch ----------------
extern "C" void kernel_launch(void* const* d_in, const int* in_sizes, int n_in,
                              void* d_out, int out_size, void* d_ws, size_t ws_size,
                              hipStream_t stream) {
    const float* x = (const float*)d_in[0];
    const int* ei = (const int*)d_in[1];
    const int* src = ei;
    const int* dst = ei + NE;
    const int* batch = (const int*)d_in[2];
    const float* W1 = (const float*)d_in[3];
    const float* b1 = (const float*)d_in[4];
    const float* W2 = (const float*)d_in[5];
    const float* b2 = (const float*)d_in[6];
    const float* W3 = (const float*)d_in[7];
    const float* b3 = (const float*)d_in[8];
    const float* Wlin = (const float*)d_in[9];
    float* out = (float*)d_out;

    float* ws = (float*)d_ws;
    float* dinv = ws;                    // 100000 (padded to 100352)
    float* H = ws + 100352;              // 9.6M
    float* B = H + (size_t)NN * CH;      // 9.6M
    float* sums = B + (size_t)NN * CH;   // 24576
    float* cnts = sums + (size_t)NG * CH;// 256

    // dinv
    k_deg_init<<<(NN + 255) / 256, 256, 0, stream>>>(dinv);
    k_deg_count<<<NE / 256, 256, 0, stream>>>(dst, dinv);
    k_deg_rsqrt<<<(NN + 255) / 256, 256, 0, stream>>>(dinv);

    // layer 1 (input x, output B) + relu
    k_gemm96<<<NN / 32, 256, 0, stream>>>(x, W1, b1, dinv, H, B);
    k_scatter<<<NE * 24 / 256, 256, 0, stream>>>(src, dst, dinv, H, B);
    k_relu<<<NN * CH / 256, 256, 0, stream>>>(B);

    // layer 2 (in-place on B)
    k_gemm96<<<NN / 32, 256, 0, stream>>>(B, W2, b2, dinv, H, B);
    k_scatter<<<NE * 24 / 256, 256, 0, stream>>>(src, dst, dinv, H, B);
    k_relu<<<NN * CH / 256, 256, 0, stream>>>(B);

    // layer 3 (no relu)
    k_gemm96<<<NN / 32, 256, 0, stream>>>(B, W3, b3, dinv, H, B);
    k_scatter<<<NE * 24 / 256, 256, 0, stream>>>(src, dst, dinv, H, B);

    // pool + final linear
    k_zero<<<(NG * CH + NG + 255) / 256, 256, 0, stream>>>(sums, NG * CH + NG);
    k_pool<<<NN * 24 / 256, 256, 0, stream>>>(batch, B, sums, cnts);
    k_final<<<(NG * OC + 255) / 256, 256, 0, stream>>>(sums, cnts, Wlin, out);
}

// Round 2
// 868.879 us; speedup vs baseline: 4.2744x; 4.2744x over previous
//
#include <hip/hip_runtime.h>

#define NN 100000   // nodes
#define NE 800000   // edges  (NE % 256 == 0)
#define NG 256      // graphs
#define CH 96       // in/hidden channels
#define OC 16       // out channels
#define NBLK 391    // ceil(NN/256)

// ---------------- CSR build ----------------
__global__ __launch_bounds__(256) void k_hist(const int* __restrict__ dst,
                                              int* __restrict__ cnt) {
    int e = blockIdx.x * 256 + threadIdx.x;
    atomicAdd(&cnt[dst[e]], 1);
}

// per-block exclusive scan; block totals out
__global__ __launch_bounds__(256) void k_scan1(const int* __restrict__ cnt,
                                               int* __restrict__ off,
                                               int* __restrict__ bsum) {
    __shared__ int sh[256];
    int t = threadIdx.x;
    int i = blockIdx.x * 256 + t;
    int v = (i < NN) ? cnt[i] : 0;
    sh[t] = v;
    __syncthreads();
    for (int d = 1; d < 256; d <<= 1) {
        int x = (t >= d) ? sh[t - d] : 0;
        __syncthreads();
        sh[t] += x;
        __syncthreads();
    }
    if (i < NN) off[i] = sh[t] - v;            // exclusive within block
    if (t == 255) bsum[blockIdx.x] = sh[255];  // block total
}

// single-block scan of block totals
__global__ __launch_bounds__(512) void k_scan2(int* __restrict__ bsum,
                                               int* __restrict__ boff) {
    __shared__ int sh[512];
    int t = threadIdx.x;
    int v = (t < NBLK) ? bsum[t] : 0;
    sh[t] = v;
    __syncthreads();
    for (int d = 1; d < 512; d <<= 1) {
        int x = (t >= d) ? sh[t - d] : 0;
        __syncthreads();
        sh[t] += x;
        __syncthreads();
    }
    if (t < NBLK) boff[t] = sh[t] - v;  // exclusive
}

// finalize offsets, init cursor, compute dinv = rsqrt(deg + 1 self-loop)
__global__ __launch_bounds__(256) void k_scan3(const int* __restrict__ cnt,
                                               int* __restrict__ off,
                                               const int* __restrict__ boff,
                                               int* __restrict__ cursor,
                                               float* __restrict__ dinv) {
    int i = blockIdx.x * 256 + threadIdx.x;
    if (i >= NN) return;
    int o = off[i] + boff[i >> 8];
    off[i] = o;
    cursor[i] = o;
    dinv[i] = rsqrtf((float)cnt[i] + 1.0f);
}

// scatter edges into CSR slots, packing (src, coef) as float2
__global__ __launch_bounds__(256) void k_build(const int* __restrict__ src,
                                               const int* __restrict__ dst,
                                               const float* __restrict__ dinv,
                                               int* __restrict__ cursor,
                                               float2* __restrict__ packed) {
    int e = blockIdx.x * 256 + threadIdx.x;
    int s = src[e];
    int d = dst[e];
    int p = atomicAdd(&cursor[d], 1);
    packed[p] = make_float2(__int_as_float(s), dinv[s] * dinv[d]);
}

// ---------------- GEMM: H = X @ W ; A = H*dinv^2 + b ----------------
// 32 nodes/block, 256 threads = 32 nodes x 8 col-groups of 12 cols.
// A may alias X: each block's X rows are staged to LDS before any write.
__global__ __launch_bounds__(256) void k_gemm96(const float* __restrict__ X,
                                                const float* __restrict__ W,
                                                const float* __restrict__ b,
                                                const float* __restrict__ dinv,
                                                float* __restrict__ H,
                                                float* __restrict__ A) {
    __shared__ __align__(16) float Ws[CH * CH];     // 36 KB
    __shared__ __align__(16) float Xs[32][CH + 1];  // padded

    const int tid = threadIdx.x;
    const int n0 = blockIdx.x * 32;

    const float4* W4 = reinterpret_cast<const float4*>(W);
    float4* Ws4 = reinterpret_cast<float4*>(Ws);
    for (int i = tid; i < CH * CH / 4; i += 256) Ws4[i] = W4[i];

    for (int i = tid; i < 32 * CH / 4; i += 256) {
        int r = i / (CH / 4);
        int c = (i % (CH / 4)) * 4;
        float4 v = *reinterpret_cast<const float4*>(&X[(size_t)(n0 + r) * CH + c]);
        Xs[r][c] = v.x; Xs[r][c + 1] = v.y; Xs[r][c + 2] = v.z; Xs[r][c + 3] = v.w;
    }
    __syncthreads();

    const int nl = tid >> 3;
    const int c0 = (tid & 7) * 12;

    float acc[12];
#pragma unroll
    for (int j = 0; j < 12; j++) acc[j] = 0.0f;

#pragma unroll 8
    for (int k = 0; k < CH; k++) {
        float xv = Xs[nl][k];
        const float* wr = &Ws[k * CH + c0];
        float4 w0 = *reinterpret_cast<const float4*>(wr);
        float4 w1 = *reinterpret_cast<const float4*>(wr + 4);
        float4 w2 = *reinterpret_cast<const float4*>(wr + 8);
        acc[0] += xv * w0.x;  acc[1] += xv * w0.y;  acc[2]  += xv * w0.z;  acc[3]  += xv * w0.w;
        acc[4] += xv * w1.x;  acc[5] += xv * w1.y;  acc[6]  += xv * w1.z;  acc[7]  += xv * w1.w;
        acc[8] += xv * w2.x;  acc[9] += xv * w2.y;  acc[10] += xv * w2.z;  acc[11] += xv * w2.w;
    }

    const int n = n0 + nl;
    const float di = dinv[n];
    const float d2 = di * di;
    float4 b0 = *reinterpret_cast<const float4*>(&b[c0]);
    float4 b1 = *reinterpret_cast<const float4*>(&b[c0 + 4]);
    float4 b2 = *reinterpret_cast<const float4*>(&b[c0 + 8]);

    float* hp = &H[(size_t)n * CH + c0];
    float* ap = &A[(size_t)n * CH + c0];
    float4 h0 = make_float4(acc[0], acc[1], acc[2], acc[3]);
    float4 h1 = make_float4(acc[4], acc[5], acc[6], acc[7]);
    float4 h2 = make_float4(acc[8], acc[9], acc[10], acc[11]);
    *reinterpret_cast<float4*>(hp) = h0;
    *reinterpret_cast<float4*>(hp + 4) = h1;
    *reinterpret_cast<float4*>(hp + 8) = h2;
    *reinterpret_cast<float4*>(ap) =
        make_float4(h0.x * d2 + b0.x, h0.y * d2 + b0.y, h0.z * d2 + b0.z, h0.w * d2 + b0.w);
    *reinterpret_cast<float4*>(ap + 4) =
        make_float4(h1.x * d2 + b1.x, h1.y * d2 + b1.y, h1.z * d2 + b1.z, h1.w * d2 + b1.w);
    *reinterpret_cast<float4*>(ap + 8) =
        make_float4(h2.x * d2 + b2.x, h2.y * d2 + b2.y, h2.z * d2 + b2.z, h2.w * d2 + b2.w);
}

// ---------------- per-dst aggregation (no atomics) ----------------
// idx -> (node n, col-group c4 of 24). All 24 lanes of a group run the same
// edge list. B[n] = (relu?) A[n] + sum_e coef_e * H[src_e].  A may alias B.
template <bool RELU>
__global__ __launch_bounds__(256) void k_aggregate(const int* __restrict__ off,
                                                   const float2* __restrict__ packed,
                                                   const float* __restrict__ A,
                                                   const float* __restrict__ H,
                                                   float* __restrict__ B) {
    int idx = blockIdx.x * 256 + threadIdx.x;  // NN*24 = 2.4M, exact
    int n = idx / 24;
    int c4 = idx - n * 24;
    int e0 = off[n];
    int e1 = (n + 1 < NN) ? off[n + 1] : NE;

    const float4* H4 = reinterpret_cast<const float4*>(H);
    float4 acc = reinterpret_cast<const float4*>(A)[(size_t)n * 24 + c4];

    for (int e = e0; e < e1; e++) {
        float2 pc = packed[e];
        int s = __float_as_int(pc.x);
        float cf = pc.y;
        float4 v = H4[(size_t)s * 24 + c4];
        acc.x += v.x * cf; acc.y += v.y * cf; acc.z += v.z * cf; acc.w += v.w * cf;
    }
    if (RELU) {
        acc.x = fmaxf(acc.x, 0.0f); acc.y = fmaxf(acc.y, 0.0f);
        acc.z = fmaxf(acc.z, 0.0f); acc.w = fmaxf(acc.w, 0.0f);
    }
    reinterpret_cast<float4*>(B)[(size_t)n * 24 + c4] = acc;
}

// ---------------- pooling ----------------
__global__ __launch_bounds__(256) void k_pool(const int* __restrict__ batch,
                                              const float* __restrict__ A,
                                              float* __restrict__ sums,
                                              float* __restrict__ cnts) {
    int idx = blockIdx.x * 256 + threadIdx.x;  // NN*24
    int n = idx / 24;
    int c4 = idx - n * 24;
    int g = batch[n];
    float4 v = *reinterpret_cast<const float4*>(&A[(size_t)n * CH + c4 * 4]);
    float* o = &sums[(size_t)g * CH + c4 * 4];
    atomicAdd(o + 0, v.x);
    atomicAdd(o + 1, v.y);
    atomicAdd(o + 2, v.z);
    atomicAdd(o + 3, v.w);
    if (c4 == 0) atomicAdd(&cnts[g], 1.0f);
}

__global__ __launch_bounds__(256) void k_final(const float* __restrict__ sums,
                                               const float* __restrict__ cnts,
                                               const float* __restrict__ Wlin,
                                               float* __restrict__ out) {
    int idx = blockIdx.x * 256 + threadIdx.x;
    if (idx >= NG * OC) return;
    int g = idx / OC;
    int o = idx - g * OC;
    float acc = 0.0f;
#pragma unroll 8
    for (int k = 0; k < CH; k++) acc += sums[g * CH + k] * Wlin[k * OC + o];
    float cnt = fmaxf(cnts[g], 1.0f);
    out[idx] = acc / cnt;
}

// ---------------- launch ----------------
extern "C" void kernel_launch(void* const* d_in, const int* in_sizes, int n_in,
                              void* d_out, int out_size, void* d_ws, size_t ws_size,
                              hipStream_t stream) {
    const float* x = (const float*)d_in[0];
    const int* ei = (const int*)d_in[1];
    const int* src = ei;
    const int* dst = ei + NE;
    const int* batch = (const int*)d_in[2];
    const float* W1 = (const float*)d_in[3];
    const float* b1 = (const float*)d_in[4];
    const float* W2 = (const float*)d_in[5];
    const float* b2 = (const float*)d_in[6];
    const float* W3 = (const float*)d_in[7];
    const float* b3 = (const float*)d_in[8];
    const float* Wlin = (const float*)d_in[9];
    float* out = (float*)d_out;

    char* ws = (char*)d_ws;
    float* H = (float*)ws;                      ws += (size_t)NN * CH * 4;  // 38.4 MB
    float* B = (float*)ws;                      ws += (size_t)NN * CH * 4;  // 38.4 MB
    float2* packed = (float2*)ws;               ws += (size_t)NE * 8;       // 6.4 MB
    float* dinv = (float*)ws;                   ws += NN * 4;
    int* cnt = (int*)ws;                        ws += NN * 4;
    int* off = (int*)ws;                        ws += NN * 4;
    int* cursor = (int*)ws;                     ws += NN * 4;
    int* bsum = (int*)ws;                       ws += 512 * 4;
    int* boff = (int*)ws;                       ws += 512 * 4;
    float* sums = (float*)ws;                   ws += NG * CH * 4;
    float* cnts = (float*)ws;                   ws += NG * 4;

    // CSR by dst + dinv
    hipMemsetAsync(cnt, 0, NN * 4, stream);
    k_hist<<<NE / 256, 256, 0, stream>>>(dst, cnt);
    k_scan1<<<NBLK, 256, 0, stream>>>(cnt, off, bsum);
    k_scan2<<<1, 512, 0, stream>>>(bsum, boff);
    k_scan3<<<NBLK, 256, 0, stream>>>(cnt, off, boff, cursor, dinv);
    k_build<<<NE / 256, 256, 0, stream>>>(src, dst, dinv, cursor, packed);

    // layer 1: x -> B (relu)
    k_gemm96<<<NN / 32, 256, 0, stream>>>(x, W1, b1, dinv, H, B);
    k_aggregate<true><<<NN * 24 / 256, 256, 0, stream>>>(off, packed, B, H, B);

    // layer 2: B -> B (relu)
    k_gemm96<<<NN / 32, 256, 0, stream>>>(B, W2, b2, dinv, H, B);
    k_aggregate<true><<<NN * 24 / 256, 256, 0, stream>>>(off, packed, B, H, B);

    // layer 3: B -> B (no relu)
    k_gemm96<<<NN / 32, 256, 0, stream>>>(B, W3, b3, dinv, H, B);
    k_aggregate<false><<<NN * 24 / 256, 256, 0, stream>>>(off, packed, B, H, B);

    // pool + final linear
    hipMemsetAsync(sums, 0, (NG * CH + NG) * 4, stream);
    k_pool<<<NN * 24 / 256, 256, 0, stream>>>(batch, B, sums, cnts);
    k_final<<<(NG * OC + 255) / 256, 256, 0, stream>>>(sums, cnts, Wlin, out);
}

// Round 3
// 498.859 us; speedup vs baseline: 7.4449x; 1.7417x over previous
//
#include <hip/hip_runtime.h>

#define NN 100000   // nodes
#define NE 800000   // edges  (NE % 256 == 0)
#define NG 256      // graphs
#define CH 96       // in/hidden channels
#define OC 16       // out channels
#define NBLK 391    // ceil(NN/256)

// ---------------- CSR build ----------------
__global__ __launch_bounds__(256) void k_hist(const int* __restrict__ dst,
                                              int* __restrict__ cnt) {
    int e = blockIdx.x * 256 + threadIdx.x;
    atomicAdd(&cnt[dst[e]], 1);
}

__global__ __launch_bounds__(256) void k_scan1(const int* __restrict__ cnt,
                                               int* __restrict__ off,
                                               int* __restrict__ bsum) {
    __shared__ int sh[256];
    int t = threadIdx.x;
    int i = blockIdx.x * 256 + t;
    int v = (i < NN) ? cnt[i] : 0;
    sh[t] = v;
    __syncthreads();
    for (int d = 1; d < 256; d <<= 1) {
        int x = (t >= d) ? sh[t - d] : 0;
        __syncthreads();
        sh[t] += x;
        __syncthreads();
    }
    if (i < NN) off[i] = sh[t] - v;
    if (t == 255) bsum[blockIdx.x] = sh[255];
}

__global__ __launch_bounds__(512) void k_scan2(int* __restrict__ bsum,
                                               int* __restrict__ boff) {
    __shared__ int sh[512];
    int t = threadIdx.x;
    int v = (t < NBLK) ? bsum[t] : 0;
    sh[t] = v;
    __syncthreads();
    for (int d = 1; d < 512; d <<= 1) {
        int x = (t >= d) ? sh[t - d] : 0;
        __syncthreads();
        sh[t] += x;
        __syncthreads();
    }
    if (t < NBLK) boff[t] = sh[t] - v;
}

__global__ __launch_bounds__(256) void k_scan3(const int* __restrict__ cnt,
                                               int* __restrict__ off,
                                               const int* __restrict__ boff,
                                               int* __restrict__ cursor,
                                               float* __restrict__ dinv) {
    int i = blockIdx.x * 256 + threadIdx.x;
    if (i >= NN) return;
    int o = off[i] + boff[i >> 8];
    off[i] = o;
    cursor[i] = o;
    dinv[i] = rsqrtf((float)cnt[i] + 1.0f);
}

__global__ __launch_bounds__(256) void k_build(const int* __restrict__ src,
                                               const int* __restrict__ dst,
                                               const float* __restrict__ dinv,
                                               int* __restrict__ cursor,
                                               float2* __restrict__ packed) {
    int e = blockIdx.x * 256 + threadIdx.x;
    int s = src[e];
    int d = dst[e];
    int p = atomicAdd(&cursor[d], 1);
    packed[p] = make_float2(__int_as_float(s), dinv[s] * dinv[d]);
}

// graph offsets from sorted batch: goff[g] = first node with batch >= g
__global__ __launch_bounds__(256) void k_goff(const int* __restrict__ batch,
                                              int* __restrict__ goff) {
    int i = blockIdx.x * 256 + threadIdx.x;
    if (i >= NN) return;
    int b = batch[i];
    int bp = (i > 0) ? batch[i - 1] : -1;
    for (int g = bp + 1; g <= b; g++) goff[g] = i;
    if (i == NN - 1)
        for (int g = b + 1; g <= NG; g++) goff[g] = NN;
}

// ---------------- GEMM: H = X @ W ; A = H*dinv^2 + b ----------------
__global__ __launch_bounds__(256) void k_gemm96(const float* __restrict__ X,
                                                const float* __restrict__ W,
                                                const float* __restrict__ b,
                                                const float* __restrict__ dinv,
                                                float* __restrict__ H,
                                                float* __restrict__ A) {
    __shared__ __align__(16) float Ws[CH * CH];
    __shared__ __align__(16) float Xs[32][CH + 1];

    const int tid = threadIdx.x;
    const int n0 = blockIdx.x * 32;

    const float4* W4 = reinterpret_cast<const float4*>(W);
    float4* Ws4 = reinterpret_cast<float4*>(Ws);
    for (int i = tid; i < CH * CH / 4; i += 256) Ws4[i] = W4[i];

    for (int i = tid; i < 32 * CH / 4; i += 256) {
        int r = i / (CH / 4);
        int c = (i % (CH / 4)) * 4;
        float4 v = *reinterpret_cast<const float4*>(&X[(size_t)(n0 + r) * CH + c]);
        Xs[r][c] = v.x; Xs[r][c + 1] = v.y; Xs[r][c + 2] = v.z; Xs[r][c + 3] = v.w;
    }
    __syncthreads();

    const int nl = tid >> 3;
    const int c0 = (tid & 7) * 12;

    float acc[12];
#pragma unroll
    for (int j = 0; j < 12; j++) acc[j] = 0.0f;

#pragma unroll 8
    for (int k = 0; k < CH; k++) {
        float xv = Xs[nl][k];
        const float* wr = &Ws[k * CH + c0];
        float4 w0 = *reinterpret_cast<const float4*>(wr);
        float4 w1 = *reinterpret_cast<const float4*>(wr + 4);
        float4 w2 = *reinterpret_cast<const float4*>(wr + 8);
        acc[0] += xv * w0.x;  acc[1] += xv * w0.y;  acc[2]  += xv * w0.z;  acc[3]  += xv * w0.w;
        acc[4] += xv * w1.x;  acc[5] += xv * w1.y;  acc[6]  += xv * w1.z;  acc[7]  += xv * w1.w;
        acc[8] += xv * w2.x;  acc[9] += xv * w2.y;  acc[10] += xv * w2.z;  acc[11] += xv * w2.w;
    }

    const int n = n0 + nl;
    const float di = dinv[n];
    const float d2 = di * di;
    float4 b0 = *reinterpret_cast<const float4*>(&b[c0]);
    float4 b1 = *reinterpret_cast<const float4*>(&b[c0 + 4]);
    float4 b2 = *reinterpret_cast<const float4*>(&b[c0 + 8]);

    float* hp = &H[(size_t)n * CH + c0];
    float* ap = &A[(size_t)n * CH + c0];
    float4 h0 = make_float4(acc[0], acc[1], acc[2], acc[3]);
    float4 h1 = make_float4(acc[4], acc[5], acc[6], acc[7]);
    float4 h2 = make_float4(acc[8], acc[9], acc[10], acc[11]);
    *reinterpret_cast<float4*>(hp) = h0;
    *reinterpret_cast<float4*>(hp + 4) = h1;
    *reinterpret_cast<float4*>(hp + 8) = h2;
    *reinterpret_cast<float4*>(ap) =
        make_float4(h0.x * d2 + b0.x, h0.y * d2 + b0.y, h0.z * d2 + b0.z, h0.w * d2 + b0.w);
    *reinterpret_cast<float4*>(ap + 4) =
        make_float4(h1.x * d2 + b1.x, h1.y * d2 + b1.y, h1.z * d2 + b1.z, h1.w * d2 + b1.w);
    *reinterpret_cast<float4*>(ap + 8) =
        make_float4(h2.x * d2 + b2.x, h2.y * d2 + b2.y, h2.z * d2 + b2.z, h2.w * d2 + b2.w);
}

// ---------------- per-dst aggregation (no atomics) ----------------
template <bool RELU>
__global__ __launch_bounds__(256) void k_aggregate(const int* __restrict__ off,
                                                   const float2* __restrict__ packed,
                                                   const float* __restrict__ A,
                                                   const float* __restrict__ H,
                                                   float* __restrict__ B) {
    int idx = blockIdx.x * 256 + threadIdx.x;
    int n = idx / 24;
    int c4 = idx - n * 24;
    int e0 = off[n];
    int e1 = (n + 1 < NN) ? off[n + 1] : NE;

    const float4* H4 = reinterpret_cast<const float4*>(H);
    float4 acc = reinterpret_cast<const float4*>(A)[(size_t)n * 24 + c4];

    for (int e = e0; e < e1; e++) {
        float2 pc = packed[e];
        int s = __float_as_int(pc.x);
        float cf = pc.y;
        float4 v = H4[(size_t)s * 24 + c4];
        acc.x += v.x * cf; acc.y += v.y * cf; acc.z += v.z * cf; acc.w += v.w * cf;
    }
    if (RELU) {
        acc.x = fmaxf(acc.x, 0.0f); acc.y = fmaxf(acc.y, 0.0f);
        acc.z = fmaxf(acc.z, 0.0f); acc.w = fmaxf(acc.w, 0.0f);
    }
    reinterpret_cast<float4*>(B)[(size_t)n * 24 + c4] = acc;
}

// ---------------- fused pool + final linear: one block per graph ----------------
// 384 threads = 16 node-lanes x 24 float4 col-groups. Zero atomics.
__global__ __launch_bounds__(384) void k_pool_linear(const int* __restrict__ goff,
                                                     const float* __restrict__ B,
                                                     const float* __restrict__ Wlin,
                                                     float* __restrict__ out) {
    __shared__ float4 sh[16][24];
    __shared__ float pooled[CH];
    int g = blockIdx.x;
    int t = threadIdx.x;
    int nl = t / 24;       // 0..15
    int c4 = t - nl * 24;  // 0..23
    int s = goff[g];
    int e = goff[g + 1];

    float4 acc = make_float4(0.f, 0.f, 0.f, 0.f);
    const float4* B4 = reinterpret_cast<const float4*>(B);
    for (int n = s + nl; n < e; n += 16) {
        float4 v = B4[(size_t)n * 24 + c4];
        acc.x += v.x; acc.y += v.y; acc.z += v.z; acc.w += v.w;
    }
    sh[nl][c4] = acc;
    __syncthreads();

    if (t < 24) {
        float4 r = make_float4(0.f, 0.f, 0.f, 0.f);
#pragma unroll
        for (int j = 0; j < 16; j++) {
            float4 v = sh[j][t];
            r.x += v.x; r.y += v.y; r.z += v.z; r.w += v.w;
        }
        float inv = 1.0f / fmaxf((float)(e - s), 1.0f);
        pooled[t * 4 + 0] = r.x * inv;
        pooled[t * 4 + 1] = r.y * inv;
        pooled[t * 4 + 2] = r.z * inv;
        pooled[t * 4 + 3] = r.w * inv;
    }
    __syncthreads();

    if (t < OC) {
        float a = 0.0f;
#pragma unroll 8
        for (int k = 0; k < CH; k++) a += pooled[k] * Wlin[k * OC + t];
        out[g * OC + t] = a;
    }
}

// ---------------- launch ----------------
extern "C" void kernel_launch(void* const* d_in, const int* in_sizes, int n_in,
                              void* d_out, int out_size, void* d_ws, size_t ws_size,
                              hipStream_t stream) {
    const float* x = (const float*)d_in[0];
    const int* ei = (const int*)d_in[1];
    const int* src = ei;
    const int* dst = ei + NE;
    const int* batch = (const int*)d_in[2];
    const float* W1 = (const float*)d_in[3];
    const float* b1 = (const float*)d_in[4];
    const float* W2 = (const float*)d_in[5];
    const float* b2 = (const float*)d_in[6];
    const float* W3 = (const float*)d_in[7];
    const float* b3 = (const float*)d_in[8];
    const float* Wlin = (const float*)d_in[9];
    float* out = (float*)d_out;

    char* ws = (char*)d_ws;
    float* H = (float*)ws;         ws += (size_t)NN * CH * 4;
    float* B = (float*)ws;         ws += (size_t)NN * CH * 4;
    float2* packed = (float2*)ws;  ws += (size_t)NE * 8;
    float* dinv = (float*)ws;      ws += NN * 4;
    int* cnt = (int*)ws;           ws += NN * 4;
    int* off = (int*)ws;           ws += NN * 4;
    int* cursor = (int*)ws;        ws += NN * 4;
    int* bsum = (int*)ws;          ws += 512 * 4;
    int* boff = (int*)ws;          ws += 512 * 4;
    int* goff = (int*)ws;          ws += (NG + 1) * 4;

    // CSR by dst + dinv + graph offsets
    hipMemsetAsync(cnt, 0, NN * 4, stream);
    k_hist<<<NE / 256, 256, 0, stream>>>(dst, cnt);
    k_scan1<<<NBLK, 256, 0, stream>>>(cnt, off, bsum);
    k_scan2<<<1, 512, 0, stream>>>(bsum, boff);
    k_scan3<<<NBLK, 256, 0, stream>>>(cnt, off, boff, cursor, dinv);
    k_build<<<NE / 256, 256, 0, stream>>>(src, dst, dinv, cursor, packed);
    k_goff<<<NBLK, 256, 0, stream>>>(batch, goff);

    // layer 1: x -> B (relu)
    k_gemm96<<<NN / 32, 256, 0, stream>>>(x, W1, b1, dinv, H, B);
    k_aggregate<true><<<NN * 24 / 256, 256, 0, stream>>>(off, packed, B, H, B);

    // layer 2: B -> B (relu)
    k_gemm96<<<NN / 32, 256, 0, stream>>>(B, W2, b2, dinv, H, B);
    k_aggregate<true><<<NN * 24 / 256, 256, 0, stream>>>(off, packed, B, H, B);

    // layer 3: B -> B (no relu)
    k_gemm96<<<NN / 32, 256, 0, stream>>>(B, W3, b3, dinv, H, B);
    k_aggregate<false><<<NN * 24 / 256, 256, 0, stream>>>(off, packed, B, H, B);

    // fused pool + linear
    k_pool_linear<<<NG, 384, 0, stream>>>(goff, B, Wlin, out);
}

// Round 4
// 455.282 us; speedup vs baseline: 8.1575x; 1.0957x over previous
//
#include <hip/hip_runtime.h>

#define NN 100000   // nodes
#define NE 800000   // edges  (NE % 256 == 0)
#define NG 256      // graphs
#define CH 96       // in/hidden channels
#define OC 16       // out channels
#define NBLK 391    // ceil(NN/256)
#define TM 128      // gemm node tile

// ---------------- CSR build ----------------
// hist + record each edge's slot (old count) so k_build needs no atomic
__global__ __launch_bounds__(256) void k_hist(const int* __restrict__ dst,
                                              int* __restrict__ cnt,
                                              int* __restrict__ slot) {
    int e = blockIdx.x * 256 + threadIdx.x;
    slot[e] = atomicAdd(&cnt[dst[e]], 1);
}

__global__ __launch_bounds__(256) void k_scan1(const int* __restrict__ cnt,
                                               int* __restrict__ off,
                                               int* __restrict__ bsum) {
    __shared__ int sh[256];
    int t = threadIdx.x;
    int i = blockIdx.x * 256 + t;
    int v = (i < NN) ? cnt[i] : 0;
    sh[t] = v;
    __syncthreads();
    for (int d = 1; d < 256; d <<= 1) {
        int x = (t >= d) ? sh[t - d] : 0;
        __syncthreads();
        sh[t] += x;
        __syncthreads();
    }
    if (i < NN) off[i] = sh[t] - v;
    if (t == 255) bsum[blockIdx.x] = sh[255];
}

__global__ __launch_bounds__(512) void k_scan2(int* __restrict__ bsum,
                                               int* __restrict__ boff) {
    __shared__ int sh[512];
    int t = threadIdx.x;
    int v = (t < NBLK) ? bsum[t] : 0;
    sh[t] = v;
    __syncthreads();
    for (int d = 1; d < 512; d <<= 1) {
        int x = (t >= d) ? sh[t - d] : 0;
        __syncthreads();
        sh[t] += x;
        __syncthreads();
    }
    if (t < NBLK) boff[t] = sh[t] - v;
}

// finalize offsets + dinv + graph boundaries (merged)
__global__ __launch_bounds__(256) void k_scan3(const int* __restrict__ cnt,
                                               int* __restrict__ off,
                                               const int* __restrict__ boff,
                                               float* __restrict__ dinv,
                                               const int* __restrict__ batch,
                                               int* __restrict__ goff) {
    int i = blockIdx.x * 256 + threadIdx.x;
    if (i >= NN) return;
    off[i] += boff[i >> 8];
    dinv[i] = rsqrtf((float)cnt[i] + 1.0f);
    int b = batch[i];
    int bp = (i > 0) ? batch[i - 1] : -1;
    for (int g = bp + 1; g <= b; g++) goff[g] = i;
    if (i == NN - 1)
        for (int g = b + 1; g <= NG; g++) goff[g] = NN;
}

// scatter edges into CSR slots (no atomics; slot precomputed in k_hist)
__global__ __launch_bounds__(256) void k_build(const int* __restrict__ src,
                                               const int* __restrict__ dst,
                                               const int* __restrict__ off,
                                               const int* __restrict__ slot,
                                               const float* __restrict__ dinv,
                                               float2* __restrict__ packed) {
    int e = blockIdx.x * 256 + threadIdx.x;
    int s = src[e];
    int d = dst[e];
    packed[off[d] + slot[e]] = make_float2(__int_as_float(s), dinv[s] * dinv[d]);
}

// ---------------- GEMM: H = X @ W ----------------
// 128-node tile; 256 threads = 32 node-groups(x4 nodes) x 8 col-groups(x12 cols).
// W streamed from L1/L2 (36 KB, hot); LDS holds only Xs -> LDS traffic /4 vs R3.
__global__ __launch_bounds__(256) void k_gemm96(const float* __restrict__ X,
                                                const float* __restrict__ W,
                                                float* __restrict__ H) {
    __shared__ __align__(16) float Xs[TM][CH + 1];  // 49.7 KB, 3 blocks/CU

    const int tid = threadIdx.x;
    const int n0 = blockIdx.x * TM;

    for (int i = tid; i < TM * CH / 4; i += 256) {
        int r = i / 24;
        int c = (i - r * 24) * 4;
        int n = n0 + r;
        float4 v = (n < NN) ? *reinterpret_cast<const float4*>(&X[(size_t)n * CH + c])
                            : make_float4(0.f, 0.f, 0.f, 0.f);
        Xs[r][c] = v.x; Xs[r][c + 1] = v.y; Xs[r][c + 2] = v.z; Xs[r][c + 3] = v.w;
    }
    __syncthreads();

    const int cg = tid & 7;   // col group: cols cg*12 .. +11
    const int ng = tid >> 3;  // node group: nodes ng*4 .. +3
    const int c0 = cg * 12;

    float acc[4][12];
#pragma unroll
    for (int j = 0; j < 4; j++)
#pragma unroll
        for (int c = 0; c < 12; c++) acc[j][c] = 0.0f;

    const float4* W4 = reinterpret_cast<const float4*>(W);

#pragma unroll 4
    for (int k = 0; k < CH; k++) {
        float4 w0 = W4[k * 24 + cg * 3 + 0];
        float4 w1 = W4[k * 24 + cg * 3 + 1];
        float4 w2 = W4[k * 24 + cg * 3 + 2];
        float xv[4];
#pragma unroll
        for (int j = 0; j < 4; j++) xv[j] = Xs[ng * 4 + j][k];
#pragma unroll
        for (int j = 0; j < 4; j++) {
            acc[j][0]  += xv[j] * w0.x;  acc[j][1]  += xv[j] * w0.y;
            acc[j][2]  += xv[j] * w0.z;  acc[j][3]  += xv[j] * w0.w;
            acc[j][4]  += xv[j] * w1.x;  acc[j][5]  += xv[j] * w1.y;
            acc[j][6]  += xv[j] * w1.z;  acc[j][7]  += xv[j] * w1.w;
            acc[j][8]  += xv[j] * w2.x;  acc[j][9]  += xv[j] * w2.y;
            acc[j][10] += xv[j] * w2.z;  acc[j][11] += xv[j] * w2.w;
        }
    }

#pragma unroll
    for (int j = 0; j < 4; j++) {
        int n = n0 + ng * 4 + j;
        if (n < NN) {
            float4* hp = reinterpret_cast<float4*>(&H[(size_t)n * CH + c0]);
            hp[0] = make_float4(acc[j][0], acc[j][1], acc[j][2], acc[j][3]);
            hp[1] = make_float4(acc[j][4], acc[j][5], acc[j][6], acc[j][7]);
            hp[2] = make_float4(acc[j][8], acc[j][9], acc[j][10], acc[j][11]);
        }
    }
}

// ---------------- per-dst aggregation (no atomics) ----------------
// B[n] = (relu?)( H[n]*dinv[n]^2 + b + sum_e coef_e * H[src_e] )
template <bool RELU>
__global__ __launch_bounds__(256) void k_aggregate(const int* __restrict__ off,
                                                   const float2* __restrict__ packed,
                                                   const float* __restrict__ dinv,
                                                   const float* __restrict__ bias,
                                                   const float* __restrict__ H,
                                                   float* __restrict__ B) {
    int idx = blockIdx.x * 256 + threadIdx.x;  // NN*24 exact
    int n = idx / 24;
    int c4 = idx - n * 24;
    int e0 = off[n];
    int e1 = (n + 1 < NN) ? off[n + 1] : NE;

    const float4* H4 = reinterpret_cast<const float4*>(H);
    float di = dinv[n];
    float d2 = di * di;
    float4 h = H4[(size_t)n * 24 + c4];
    float4 bb = reinterpret_cast<const float4*>(bias)[c4];
    float4 acc = make_float4(h.x * d2 + bb.x, h.y * d2 + bb.y,
                             h.z * d2 + bb.z, h.w * d2 + bb.w);

    int e = e0;
    for (; e + 4 <= e1; e += 4) {  // 4 outstanding gathers
        float2 p0 = packed[e + 0];
        float2 p1 = packed[e + 1];
        float2 p2 = packed[e + 2];
        float2 p3 = packed[e + 3];
        float4 v0 = H4[(size_t)__float_as_int(p0.x) * 24 + c4];
        float4 v1 = H4[(size_t)__float_as_int(p1.x) * 24 + c4];
        float4 v2 = H4[(size_t)__float_as_int(p2.x) * 24 + c4];
        float4 v3 = H4[(size_t)__float_as_int(p3.x) * 24 + c4];
        acc.x += v0.x * p0.y + v1.x * p1.y + v2.x * p2.y + v3.x * p3.y;
        acc.y += v0.y * p0.y + v1.y * p1.y + v2.y * p2.y + v3.y * p3.y;
        acc.z += v0.z * p0.y + v1.z * p1.y + v2.z * p2.y + v3.z * p3.y;
        acc.w += v0.w * p0.y + v1.w * p1.y + v2.w * p2.y + v3.w * p3.y;
    }
    for (; e < e1; e++) {
        float2 pc = packed[e];
        float4 v = H4[(size_t)__float_as_int(pc.x) * 24 + c4];
        acc.x += v.x * pc.y; acc.y += v.y * pc.y;
        acc.z += v.z * pc.y; acc.w += v.w * pc.y;
    }
    if (RELU) {
        acc.x = fmaxf(acc.x, 0.0f); acc.y = fmaxf(acc.y, 0.0f);
        acc.z = fmaxf(acc.z, 0.0f); acc.w = fmaxf(acc.w, 0.0f);
    }
    reinterpret_cast<float4*>(B)[(size_t)n * 24 + c4] = acc;
}

// ---------------- fused pool + final linear ----------------
__global__ __launch_bounds__(384) void k_pool_linear(const int* __restrict__ goff,
                                                     const float* __restrict__ B,
                                                     const float* __restrict__ Wlin,
                                                     float* __restrict__ out) {
    __shared__ float4 sh[16][24];
    __shared__ float pooled[CH];
    int g = blockIdx.x;
    int t = threadIdx.x;
    int nl = t / 24;
    int c4 = t - nl * 24;
    int s = goff[g];
    int e = goff[g + 1];

    float4 acc = make_float4(0.f, 0.f, 0.f, 0.f);
    const float4* B4 = reinterpret_cast<const float4*>(B);
    for (int n = s + nl; n < e; n += 16) {
        float4 v = B4[(size_t)n * 24 + c4];
        acc.x += v.x; acc.y += v.y; acc.z += v.z; acc.w += v.w;
    }
    sh[nl][c4] = acc;
    __syncthreads();

    if (t < 24) {
        float4 r = make_float4(0.f, 0.f, 0.f, 0.f);
#pragma unroll
        for (int j = 0; j < 16; j++) {
            float4 v = sh[j][t];
            r.x += v.x; r.y += v.y; r.z += v.z; r.w += v.w;
        }
        float inv = 1.0f / fmaxf((float)(e - s), 1.0f);
        pooled[t * 4 + 0] = r.x * inv;
        pooled[t * 4 + 1] = r.y * inv;
        pooled[t * 4 + 2] = r.z * inv;
        pooled[t * 4 + 3] = r.w * inv;
    }
    __syncthreads();

    if (t < OC) {
        float a = 0.0f;
#pragma unroll 8
        for (int k = 0; k < CH; k++) a += pooled[k] * Wlin[k * OC + t];
        out[g * OC + t] = a;
    }
}

// ---------------- launch ----------------
extern "C" void kernel_launch(void* const* d_in, const int* in_sizes, int n_in,
                              void* d_out, int out_size, void* d_ws, size_t ws_size,
                              hipStream_t stream) {
    const float* x = (const float*)d_in[0];
    const int* ei = (const int*)d_in[1];
    const int* src = ei;
    const int* dst = ei + NE;
    const int* batch = (const int*)d_in[2];
    const float* W1 = (const float*)d_in[3];
    const float* b1 = (const float*)d_in[4];
    const float* W2 = (const float*)d_in[5];
    const float* b2 = (const float*)d_in[6];
    const float* W3 = (const float*)d_in[7];
    const float* b3 = (const float*)d_in[8];
    const float* Wlin = (const float*)d_in[9];
    float* out = (float*)d_out;

    char* ws = (char*)d_ws;
    float* H = (float*)ws;         ws += (size_t)NN * CH * 4;  // 38.4 MB
    float* B = (float*)ws;         ws += (size_t)NN * CH * 4;  // 38.4 MB
    float2* packed = (float2*)ws;  ws += (size_t)NE * 8;       // 6.4 MB
    float* dinv = (float*)ws;      ws += NN * 4;
    int* cnt = (int*)ws;           ws += NN * 4;
    int* off = (int*)ws;           ws += NN * 4;
    int* bsum = (int*)ws;          ws += 512 * 4;
    int* boff = (int*)ws;          ws += 512 * 4;
    int* goff = (int*)ws;          ws += (NG + 1) * 4;
    int* slot = (int*)B;  // B is dead until aggregate-1; reuse for edge slots

    // CSR by dst + dinv + graph offsets
    hipMemsetAsync(cnt, 0, NN * 4, stream);
    k_hist<<<NE / 256, 256, 0, stream>>>(dst, cnt, slot);
    k_scan1<<<NBLK, 256, 0, stream>>>(cnt, off, bsum);
    k_scan2<<<1, 512, 0, stream>>>(bsum, boff);
    k_scan3<<<NBLK, 256, 0, stream>>>(cnt, off, boff, dinv, batch, goff);
    k_build<<<NE / 256, 256, 0, stream>>>(src, dst, off, slot, dinv, packed);

    // layer 1: x -> H -> B (relu)
    k_gemm96<<<(NN + TM - 1) / TM, 256, 0, stream>>>(x, W1, H);
    k_aggregate<true><<<NN * 24 / 256, 256, 0, stream>>>(off, packed, dinv, b1, H, B);

    // layer 2: B -> H -> B (relu)
    k_gemm96<<<(NN + TM - 1) / TM, 256, 0, stream>>>(B, W2, H);
    k_aggregate<true><<<NN * 24 / 256, 256, 0, stream>>>(off, packed, dinv, b2, H, B);

    // layer 3: B -> H -> B (no relu)
    k_gemm96<<<(NN + TM - 1) / TM, 256, 0, stream>>>(B, W3, H);
    k_aggregate<false><<<NN * 24 / 256, 256, 0, stream>>>(off, packed, dinv, b3, H, B);

    // fused pool + linear
    k_pool_linear<<<NG, 384, 0, stream>>>(goff, B, Wlin, out);
}